// Round 7
// baseline (79.303 us; speedup 1.0000x reference)
//
#include <hip/hip_runtime.h>

#define NK 19
#define NB 8
#define NC 256
#define NP 8192           // 64*128
#define NBP (NB*NP)       // 65536

typedef unsigned char u8;

// ---------------- kernel 1: argmax over classes + integer counts ----------------
__global__ __launch_bounds__(256) void k_argmax(const float* __restrict__ target,
                                                u8* __restrict__ lab,
                                                int* __restrict__ counts) {
  __shared__ float tl[256 * NK];                 // 19456 B
  __shared__ int lcnt[NK];
  if (threadIdx.x < NK) lcnt[threadIdx.x] = 0;
  const float4* src = (const float4*)(target + (size_t)blockIdx.x * (256 * NK));
  float4* dst = (float4*)tl;
  for (int i = threadIdx.x; i < 256 * NK / 4; i += 256) dst[i] = src[i];
  __syncthreads();
  const float* row = &tl[threadIdx.x * NK];
  float best = row[0]; int bk = 0;
#pragma unroll
  for (int k = 1; k < NK; ++k) { float v = row[k]; if (v > best) { best = v; bk = k; } }
  int g = blockIdx.x * 256 + threadIdx.x;
  lab[g] = (u8)bk;
  atomicAdd(&lcnt[bk], 1);
  __syncthreads();
  int b = g >> 13;                               // / NP (block is within one b)
  if (threadIdx.x < NK) atomicAdd(&counts[b * NK + threadIdx.x], lcnt[threadIdx.x]);
}

// ---------------- kernel 2: class sums via branchless REGISTER accumulators ----------------
// No LDS in the hot loop: per element compute mask (lab==k) once, fma into
// statically-indexed register accumulators for S and T. LDS used only for the
// final 38-row tree fold (no RMW chains, no zeroing — every cell is written).
__global__ __launch_bounds__(256) void k_sums(const float* __restrict__ fS,
                                              const float* __restrict__ fT,
                                              const u8* __restrict__ lab,
                                              float* __restrict__ sums) {
  __shared__ float bins[2 * NK * 256];           // 38912 B
  int id = blockIdx.x;                           // [0, 2048): b(8) x c(256)
  int b = id >> 8;
  int c = id & 255;
  int t = threadIdx.x;
  const float4* rS = (const float4*)(fS + ((size_t)(b * NC + c)) * NP);
  const float4* rT = (const float4*)(fT + ((size_t)(b * NC + c)) * NP);
  const uchar4* lb = (const uchar4*)(lab + b * NP);
  float aS[NK], aT[NK];
#pragma unroll
  for (int k = 0; k < NK; ++k) { aS[k] = 0.f; aT[k] = 0.f; }
  // 1-deep software pipeline: loads for i+1 in flight during compute of i
  uchar4 l = lb[t];
  float4 vS = rS[t];
  float4 vT = rT[t];
#pragma unroll
  for (int i = 0; i < 8; ++i) {
    uchar4 lc = l; float4 wS = vS, wT = vT;
    if (i < 7) {
      int p4 = (i + 1) * 256 + t;
      l = lb[p4]; vS = rS[p4]; vT = rT[p4];
    }
    int lx = lc.x, ly = lc.y, lz = lc.z, lw = lc.w;
#pragma unroll
    for (int k = 0; k < NK; ++k) {
      float mx = (lx == k) ? 1.f : 0.f;
      float my = (ly == k) ? 1.f : 0.f;
      float mz = (lz == k) ? 1.f : 0.f;
      float mw = (lw == k) ? 1.f : 0.f;
      aS[k] = fmaf(wS.x, mx, aS[k]);
      aS[k] = fmaf(wS.y, my, aS[k]);
      aS[k] = fmaf(wS.z, mz, aS[k]);
      aS[k] = fmaf(wS.w, mw, aS[k]);
      aT[k] = fmaf(wT.x, mx, aT[k]);
      aT[k] = fmaf(wT.y, my, aT[k]);
      aT[k] = fmaf(wT.z, mz, aT[k]);
      aT[k] = fmaf(wT.w, mw, aT[k]);
    }
  }
  // dump accumulators: rows 0..18 = S, 19..37 = T; column t -> conflict-free
#pragma unroll
  for (int k = 0; k < NK; ++k) {
    bins[k * 256 + t]        = aS[k];
    bins[(NK + k) * 256 + t] = aT[k];
  }
  __syncthreads();
  // tree fold: 38 rows, each 64 float4
  float4* F = (float4*)bins;
  for (int j = t; j < 38 * 32; j += 256) { int r = j >> 5, i = j & 31; F[r * 64 + i] += F[r * 64 + i + 32]; }
  __syncthreads();
  for (int j = t; j < 38 * 16; j += 256) { int r = j >> 4, i = j & 15; F[r * 64 + i] += F[r * 64 + i + 16]; }
  __syncthreads();
  for (int j = t; j < 38 * 8;  j += 256) { int r = j >> 3, i = j & 7;  F[r * 64 + i] += F[r * 64 + i + 8];  }
  __syncthreads();
  for (int j = t; j < 38 * 4;  j += 256) { int r = j >> 2, i = j & 3;  F[r * 64 + i] += F[r * 64 + i + 4];  }
  __syncthreads();
  if (t < 38) {
    float4 a = F[t * 64 + 0], b4 = F[t * 64 + 1], c4 = F[t * 64 + 2], d4 = F[t * 64 + 3];
    float s = (((a.x + a.y) + (a.z + a.w)) + ((b4.x + b4.y) + (b4.z + b4.w)))
            + (((c4.x + c4.y) + (c4.z + c4.w)) + ((d4.x + d4.y) + (d4.z + d4.w)));
    int f2 = t / NK, k = t - f2 * NK;
    sums[((size_t)((f2 * NB + b) * NC + c)) * NK + k] = s;
  }
}

// ---------------- kernel 3: means + per-(f,b,k) center norms ----------------
__global__ __launch_bounds__(256) void k_means(const float* __restrict__ sums,
                                               const int* __restrict__ counts,
                                               float* __restrict__ means,
                                               float* __restrict__ cnorm) {
  int b = blockIdx.x / NK, k = blockIdx.x % NK;
  int c = threadIdx.x;
  float cnt = (float)counts[b * NK + k] + 1e-6f;
  size_t iS = ((size_t)(b * NC + c)) * NK + k;
  size_t iT = ((size_t)((NB + b) * NC + c)) * NK + k;
  float mS = sums[iS] / cnt;
  float mT = sums[iT] / cnt;
  means[iS] = mS;
  means[iT] = mT;
  float sS = mS * mS, sT = mT * mT;
#pragma unroll
  for (int off = 32; off > 0; off >>= 1) { sS += __shfl_down(sS, off, 64); sT += __shfl_down(sT, off, 64); }
  __shared__ float redS[4], redT[4];
  int wid = threadIdx.x >> 6, lane = threadIdx.x & 63;
  if (lane == 0) { redS[wid] = sS; redT[wid] = sT; }
  __syncthreads();
  if (threadIdx.x == 0) {
    float tS = redS[0] + redS[1] + redS[2] + redS[3];
    float tT = redT[0] + redT[1] + redT[2] + redT[3];
    cnorm[b * NK + k]           = fmaxf(sqrtf(tS), 1e-8f);
    cnorm[NB * NK + b * NK + k] = fmaxf(sqrtf(tT), 1e-8f);
  }
}

// ---------------- kernel 4: per-pixel cosine + squared diff (4-way channel split) ----------------
__global__ __launch_bounds__(256) void k_cos(const float* __restrict__ fS,
                                             const float* __restrict__ fT,
                                             const u8* __restrict__ lab,
                                             const float* __restrict__ means,
                                             const float* __restrict__ cnorm,
                                             float* __restrict__ partial) {
  __shared__ float R[1024];                      // 4 KB
  int b = blockIdx.x >> 7, pt = blockIdx.x & 127;
  int t = threadIdx.x;
  int px = t & 63, cg = t >> 6;                  // 4 channel-groups x 64 pixels
  int p = pt * 64 + px;
  int k = lab[b * NP + p];
  const float* rs = fS + (size_t)b * NC * NP + p;
  const float* rt = fT + (size_t)b * NC * NP + p;
  const float* mSb = means + (size_t)(b * NC) * NK;
  const float* mTb = means + (size_t)((NB + b) * NC) * NK;
  float dS = 0.f, nS = 0.f, dT = 0.f, nT = 0.f;
  int c0 = cg * 64;
#pragma unroll 8
  for (int j = 0; j < 64; ++j) {
    int c = c0 + j;
    float vS = rs[(size_t)c * NP];
    float vT = rt[(size_t)c * NP];
    float cS = mSb[c * NK + k];
    float cT = mTb[c * NK + k];
    dS += vS * cS; nS += vS * vS;
    dT += vT * cT; nT += vT * vT;
  }
  R[t] = dS; R[256 + t] = nS; R[512 + t] = dT; R[768 + t] = nT;
  __syncthreads();
  if (t < 64) {
    dS = R[t]       + R[64 + t]  + R[128 + t] + R[192 + t];
    nS = R[256 + t] + R[320 + t] + R[384 + t] + R[448 + t];
    dT = R[512 + t] + R[576 + t] + R[640 + t] + R[704 + t];
    nT = R[768 + t] + R[832 + t] + R[896 + t] + R[960 + t];
    float cnS = cnorm[b * NK + k];
    float cnT = cnorm[NB * NK + b * NK + k];
    float cosS = dS / (fmaxf(sqrtf(nS), 1e-8f) * cnS);
    float cosT = dT / (fmaxf(sqrtf(nT), 1e-8f) * cnT);
    float d = cosS - cosT;
    float v = d * d;
#pragma unroll
    for (int off = 32; off > 0; off >>= 1) v += __shfl_down(v, off, 64);
    if (px == 0) partial[blockIdx.x] = v;
  }
}

// ---------------- kernel 5: final deterministic reduction (1024 partials) ----------------
__global__ __launch_bounds__(256) void k_final(const float* __restrict__ partial,
                                               float* __restrict__ out) {
  int t = threadIdx.x;
  float v = partial[t] + partial[256 + t] + partial[512 + t] + partial[768 + t];
#pragma unroll
  for (int off = 32; off > 0; off >>= 1) v += __shfl_down(v, off, 64);
  __shared__ float red[4];
  int wid = t >> 6, lane = t & 63;
  if (lane == 0) red[wid] = v;
  __syncthreads();
  if (t == 0) out[0] = (red[0] + red[1] + red[2] + red[3]) * (1.0f / (float)NBP);
}

// ---------------- launch ----------------
extern "C" void kernel_launch(void* const* d_in, const int* in_sizes, int n_in,
                              void* d_out, int out_size, void* d_ws, size_t ws_size,
                              hipStream_t stream) {
  const float* fS     = (const float*)d_in[0];
  const float* fT     = (const float*)d_in[1];
  const float* target = (const float*)d_in[2];
  char* ws = (char*)d_ws;
  u8*    lab     = (u8*)   (ws + 0);        // 65536 B
  int*   counts  = (int*)  (ws + 65536);    // 608 B (pad to 66560)
  float* sums    = (float*)(ws + 66560);    // 311296 B -> 377856
  float* means   = (float*)(ws + 377856);   // 311296 B -> 689152
  float* cnorm   = (float*)(ws + 689152);   // 1216 B (pad to 690432)
  float* partial = (float*)(ws + 690432);   // 4096 B
  float* out = (float*)d_out;

  hipMemsetAsync(counts, 0, NB * NK * sizeof(int), stream);
  k_argmax<<<NBP / 256,   256, 0, stream>>>(target, lab, counts);
  k_sums  <<<NB * NC,     256, 0, stream>>>(fS, fT, lab, sums);
  k_means <<<NB * NK,     256, 0, stream>>>(sums, counts, means, cnorm);
  k_cos   <<<NB * (NP / 64), 256, 0, stream>>>(fS, fT, lab, means, cnorm, partial);
  k_final <<<1, 256, 0, stream>>>(partial, out);
}

// Round 8
// 73.259 us; speedup vs baseline: 1.0825x; 1.0825x over previous
//
#include <hip/hip_runtime.h>

#define NK 19
#define NB 8
#define NC 256
#define NP 8192           // 64*128
#define NBP (NB*NP)       // 65536

typedef unsigned char u8;

// ---------------- kernel 1: argmax over classes + integer counts ----------------
__global__ __launch_bounds__(256) void k_argmax(const float* __restrict__ target,
                                                u8* __restrict__ lab,
                                                int* __restrict__ counts) {
  __shared__ float tl[256 * NK];                 // 19456 B
  __shared__ int lcnt[NK];
  if (threadIdx.x < NK) lcnt[threadIdx.x] = 0;
  const float4* src = (const float4*)(target + (size_t)blockIdx.x * (256 * NK));
  float4* dst = (float4*)tl;
  for (int i = threadIdx.x; i < 256 * NK / 4; i += 256) dst[i] = src[i];
  __syncthreads();
  const float* row = &tl[threadIdx.x * NK];
  float best = row[0]; int bk = 0;
#pragma unroll
  for (int k = 1; k < NK; ++k) { float v = row[k]; if (v > best) { best = v; bk = k; } }
  int g = blockIdx.x * 256 + threadIdx.x;
  lab[g] = (u8)bk;
  atomicAdd(&lcnt[bk], 1);
  __syncthreads();
  int b = g >> 13;                               // / NP (block is within one b)
  if (threadIdx.x < NK) atomicAdd(&counts[b * NK + threadIdx.x], lcnt[threadIdx.x]);
}

// ---------------- kernel 2: class sums, 2 channels/block, masks amortized ----------------
// Masks (lab==k) computed ONCE per pixel, reused by 4 streams (2ch x 2feat).
// float2 accumulators invite v_pk_fma_f32. LDS only for the final fold
// (two rounds: S then T, reusing the same 38 KB).
__global__ __launch_bounds__(256) void k_sums(const float* __restrict__ fS,
                                              const float* __restrict__ fT,
                                              const u8* __restrict__ lab,
                                              float* __restrict__ sums) {
  __shared__ float bins[2 * NK * 256];           // 38912 B (38 rows x 256)
  int id = blockIdx.x;                           // [0, 1024): b(8) x cpair(128)
  int b = id >> 7;
  int c0 = (id & 127) * 2;
  int t = threadIdx.x;
  const float* baseS = fS + ((size_t)(b * NC + c0)) * NP;
  const float* baseT = fT + ((size_t)(b * NC + c0)) * NP;
  const float4* rS0 = (const float4*)baseS;
  const float4* rS1 = (const float4*)(baseS + NP);
  const float4* rT0 = (const float4*)baseT;
  const float4* rT1 = (const float4*)(baseT + NP);
  const uchar4* lb  = (const uchar4*)(lab + b * NP);
  float2 aS[NK], aT[NK];
#pragma unroll
  for (int k = 0; k < NK; ++k) { aS[k] = make_float2(0.f, 0.f); aT[k] = make_float2(0.f, 0.f); }
  // 1-deep pipeline
  uchar4 l  = lb[t];
  float4 s0 = rS0[t], s1 = rS1[t], t0 = rT0[t], t1 = rT1[t];
#pragma unroll
  for (int i = 0; i < 8; ++i) {
    uchar4 lc = l; float4 wS0 = s0, wS1 = s1, wT0 = t0, wT1 = t1;
    if (i < 7) {
      int p4 = (i + 1) * 256 + t;
      l = lb[p4]; s0 = rS0[p4]; s1 = rS1[p4]; t0 = rT0[p4]; t1 = rT1[p4];
    }
    int lx = lc.x, ly = lc.y, lz = lc.z, lw = lc.w;
#pragma unroll
    for (int k = 0; k < NK; ++k) {
      float mx = (lx == k) ? 1.f : 0.f;
      float my = (ly == k) ? 1.f : 0.f;
      float mz = (lz == k) ? 1.f : 0.f;
      float mw = (lw == k) ? 1.f : 0.f;
      // pixel-slot x: pair (ch0,ch1) scaled by shared mask -> v_pk_fma candidates
      aS[k].x = fmaf(wS0.x, mx, aS[k].x); aS[k].y = fmaf(wS1.x, mx, aS[k].y);
      aT[k].x = fmaf(wT0.x, mx, aT[k].x); aT[k].y = fmaf(wT1.x, mx, aT[k].y);
      aS[k].x = fmaf(wS0.y, my, aS[k].x); aS[k].y = fmaf(wS1.y, my, aS[k].y);
      aT[k].x = fmaf(wT0.y, my, aT[k].x); aT[k].y = fmaf(wT1.y, my, aT[k].y);
      aS[k].x = fmaf(wS0.z, mz, aS[k].x); aS[k].y = fmaf(wS1.z, mz, aS[k].y);
      aT[k].x = fmaf(wT0.z, mz, aT[k].x); aT[k].y = fmaf(wT1.z, mz, aT[k].y);
      aS[k].x = fmaf(wS0.w, mw, aS[k].x); aS[k].y = fmaf(wS1.w, mw, aS[k].y);
      aT[k].x = fmaf(wT0.w, mw, aT[k].x); aT[k].y = fmaf(wT1.w, mw, aT[k].y);
    }
  }
  float4* F = (float4*)bins;
  // ---- fold round 1: S (rows 2k+ch) ----
#pragma unroll
  for (int k = 0; k < NK; ++k) {
    bins[(2 * k + 0) * 256 + t] = aS[k].x;
    bins[(2 * k + 1) * 256 + t] = aS[k].y;
  }
  __syncthreads();
  for (int j = t; j < 38 * 32; j += 256) { int r = j >> 5, i = j & 31; F[r * 64 + i] += F[r * 64 + i + 32]; }
  __syncthreads();
  for (int j = t; j < 38 * 16; j += 256) { int r = j >> 4, i = j & 15; F[r * 64 + i] += F[r * 64 + i + 16]; }
  __syncthreads();
  for (int j = t; j < 38 * 8;  j += 256) { int r = j >> 3, i = j & 7;  F[r * 64 + i] += F[r * 64 + i + 8];  }
  __syncthreads();
  for (int j = t; j < 38 * 4;  j += 256) { int r = j >> 2, i = j & 3;  F[r * 64 + i] += F[r * 64 + i + 4];  }
  __syncthreads();
  if (t < 38) {
    float4 a = F[t * 64 + 0], b4 = F[t * 64 + 1], c4 = F[t * 64 + 2], d4 = F[t * 64 + 3];
    float s = (((a.x + a.y) + (a.z + a.w)) + ((b4.x + b4.y) + (b4.z + b4.w)))
            + (((c4.x + c4.y) + (c4.z + c4.w)) + ((d4.x + d4.y) + (d4.z + d4.w)));
    int k = t >> 1, ch = t & 1;
    sums[((size_t)((0 * NB + b) * NC + c0 + ch)) * NK + k] = s;
  }
  __syncthreads();
  // ---- fold round 2: T ----
#pragma unroll
  for (int k = 0; k < NK; ++k) {
    bins[(2 * k + 0) * 256 + t] = aT[k].x;
    bins[(2 * k + 1) * 256 + t] = aT[k].y;
  }
  __syncthreads();
  for (int j = t; j < 38 * 32; j += 256) { int r = j >> 5, i = j & 31; F[r * 64 + i] += F[r * 64 + i + 32]; }
  __syncthreads();
  for (int j = t; j < 38 * 16; j += 256) { int r = j >> 4, i = j & 15; F[r * 64 + i] += F[r * 64 + i + 16]; }
  __syncthreads();
  for (int j = t; j < 38 * 8;  j += 256) { int r = j >> 3, i = j & 7;  F[r * 64 + i] += F[r * 64 + i + 8];  }
  __syncthreads();
  for (int j = t; j < 38 * 4;  j += 256) { int r = j >> 2, i = j & 3;  F[r * 64 + i] += F[r * 64 + i + 4];  }
  __syncthreads();
  if (t < 38) {
    float4 a = F[t * 64 + 0], b4 = F[t * 64 + 1], c4 = F[t * 64 + 2], d4 = F[t * 64 + 3];
    float s = (((a.x + a.y) + (a.z + a.w)) + ((b4.x + b4.y) + (b4.z + b4.w)))
            + (((c4.x + c4.y) + (c4.z + c4.w)) + ((d4.x + d4.y) + (d4.z + d4.w)));
    int k = t >> 1, ch = t & 1;
    sums[((size_t)((1 * NB + b) * NC + c0 + ch)) * NK + k] = s;
  }
}

// ---------------- kernel 3: means + per-(f,b,k) center norms ----------------
__global__ __launch_bounds__(256) void k_means(const float* __restrict__ sums,
                                               const int* __restrict__ counts,
                                               float* __restrict__ means,
                                               float* __restrict__ cnorm) {
  int b = blockIdx.x / NK, k = blockIdx.x % NK;
  int c = threadIdx.x;
  float cnt = (float)counts[b * NK + k] + 1e-6f;
  size_t iS = ((size_t)(b * NC + c)) * NK + k;
  size_t iT = ((size_t)((NB + b) * NC + c)) * NK + k;
  float mS = sums[iS] / cnt;
  float mT = sums[iT] / cnt;
  means[iS] = mS;
  means[iT] = mT;
  float sS = mS * mS, sT = mT * mT;
#pragma unroll
  for (int off = 32; off > 0; off >>= 1) { sS += __shfl_down(sS, off, 64); sT += __shfl_down(sT, off, 64); }
  __shared__ float redS[4], redT[4];
  int wid = threadIdx.x >> 6, lane = threadIdx.x & 63;
  if (lane == 0) { redS[wid] = sS; redT[wid] = sT; }
  __syncthreads();
  if (threadIdx.x == 0) {
    float tS = redS[0] + redS[1] + redS[2] + redS[3];
    float tT = redT[0] + redT[1] + redT[2] + redT[3];
    cnorm[b * NK + k]           = fmaxf(sqrtf(tS), 1e-8f);
    cnorm[NB * NK + b * NK + k] = fmaxf(sqrtf(tT), 1e-8f);
  }
}

// ---------------- kernel 4: per-pixel cosine + squared diff (4-way channel split) ----------------
__global__ __launch_bounds__(256) void k_cos(const float* __restrict__ fS,
                                             const float* __restrict__ fT,
                                             const u8* __restrict__ lab,
                                             const float* __restrict__ means,
                                             const float* __restrict__ cnorm,
                                             float* __restrict__ partial) {
  __shared__ float R[1024];                      // 4 KB
  int b = blockIdx.x >> 7, pt = blockIdx.x & 127;
  int t = threadIdx.x;
  int px = t & 63, cg = t >> 6;                  // 4 channel-groups x 64 pixels
  int p = pt * 64 + px;
  int k = lab[b * NP + p];
  const float* rs = fS + (size_t)b * NC * NP + p;
  const float* rt = fT + (size_t)b * NC * NP + p;
  const float* mSb = means + (size_t)(b * NC) * NK;
  const float* mTb = means + (size_t)((NB + b) * NC) * NK;
  float dS = 0.f, nS = 0.f, dT = 0.f, nT = 0.f;
  int c0 = cg * 64;
#pragma unroll 8
  for (int j = 0; j < 64; ++j) {
    int c = c0 + j;
    float vS = rs[(size_t)c * NP];
    float vT = rt[(size_t)c * NP];
    float cS = mSb[c * NK + k];
    float cT = mTb[c * NK + k];
    dS += vS * cS; nS += vS * vS;
    dT += vT * cT; nT += vT * vT;
  }
  R[t] = dS; R[256 + t] = nS; R[512 + t] = dT; R[768 + t] = nT;
  __syncthreads();
  if (t < 64) {
    dS = R[t]       + R[64 + t]  + R[128 + t] + R[192 + t];
    nS = R[256 + t] + R[320 + t] + R[384 + t] + R[448 + t];
    dT = R[512 + t] + R[576 + t] + R[640 + t] + R[704 + t];
    nT = R[768 + t] + R[832 + t] + R[896 + t] + R[960 + t];
    float cnS = cnorm[b * NK + k];
    float cnT = cnorm[NB * NK + b * NK + k];
    float cosS = dS / (fmaxf(sqrtf(nS), 1e-8f) * cnS);
    float cosT = dT / (fmaxf(sqrtf(nT), 1e-8f) * cnT);
    float d = cosS - cosT;
    float v = d * d;
#pragma unroll
    for (int off = 32; off > 0; off >>= 1) v += __shfl_down(v, off, 64);
    if (px == 0) partial[blockIdx.x] = v;
  }
}

// ---------------- kernel 5: final deterministic reduction (1024 partials) ----------------
__global__ __launch_bounds__(256) void k_final(const float* __restrict__ partial,
                                               float* __restrict__ out) {
  int t = threadIdx.x;
  float v = partial[t] + partial[256 + t] + partial[512 + t] + partial[768 + t];
#pragma unroll
  for (int off = 32; off > 0; off >>= 1) v += __shfl_down(v, off, 64);
  __shared__ float red[4];
  int wid = t >> 6, lane = t & 63;
  if (lane == 0) red[wid] = v;
  __syncthreads();
  if (t == 0) out[0] = (red[0] + red[1] + red[2] + red[3]) * (1.0f / (float)NBP);
}

// ---------------- launch ----------------
extern "C" void kernel_launch(void* const* d_in, const int* in_sizes, int n_in,
                              void* d_out, int out_size, void* d_ws, size_t ws_size,
                              hipStream_t stream) {
  const float* fS     = (const float*)d_in[0];
  const float* fT     = (const float*)d_in[1];
  const float* target = (const float*)d_in[2];
  char* ws = (char*)d_ws;
  u8*    lab     = (u8*)   (ws + 0);        // 65536 B
  int*   counts  = (int*)  (ws + 65536);    // 608 B (pad to 66560)
  float* sums    = (float*)(ws + 66560);    // 311296 B -> 377856
  float* means   = (float*)(ws + 377856);   // 311296 B -> 689152
  float* cnorm   = (float*)(ws + 689152);   // 1216 B (pad to 690432)
  float* partial = (float*)(ws + 690432);   // 4096 B
  float* out = (float*)d_out;

  hipMemsetAsync(counts, 0, NB * NK * sizeof(int), stream);
  k_argmax<<<NBP / 256,   256, 0, stream>>>(target, lab, counts);
  k_sums  <<<NB * 128,    256, 0, stream>>>(fS, fT, lab, sums);
  k_means <<<NB * NK,     256, 0, stream>>>(sums, counts, means, cnorm);
  k_cos   <<<NB * (NP / 64), 256, 0, stream>>>(fS, fT, lab, means, cnorm, partial);
  k_final <<<1, 256, 0, stream>>>(partial, out);
}